// Round 2
// baseline (230.885 us; speedup 1.0000x reference)
//
#include <hip/hip_runtime.h>
#include <hip/hip_bf16.h>
#include <stdint.h>

typedef __hip_bfloat16 bf16_t;
typedef __attribute__((ext_vector_type(8))) __bf16 bf16x8;
typedef __attribute__((ext_vector_type(4))) float f32x4;
typedef __attribute__((ext_vector_type(8))) unsigned short ushort8;
typedef __attribute__((ext_vector_type(2))) unsigned long long u64x2;

#define TILE 128
#define BK 32
#define THREADS 256

// ---------------- quantize: q = rint(v*100)/100, cast to bf16 ----------------
// Stores are agent-scope so the following GEMM kernel (possibly on another XCD,
// possibly inside a graph replay with weakened interior fences) always sees them.
__global__ __launch_bounds__(256) void quant_bf16_kernel(
    const float* __restrict__ in, bf16_t* __restrict__ out, long n8) {
  long idx = (long)blockIdx.x * blockDim.x + threadIdx.x;
  long stride = (long)gridDim.x * blockDim.x;
  for (long i = idx; i < n8; i += stride) {
    const float4* p = reinterpret_cast<const float4*>(in + i * 8);
    float4 v0 = p[0];
    float4 v1 = p[1];
    float vv[8] = {v0.x, v0.y, v0.z, v0.w, v1.x, v1.y, v1.z, v1.w};
    ushort8 r;
#pragma unroll
    for (int j = 0; j < 8; ++j) {
      float q = rintf(vv[j] * 100.0f) / 100.0f;  // half-to-even, matches jnp.round
      __hip_bfloat16 h = __float2bfloat16(q);
      r[j] = __builtin_bit_cast(unsigned short, h);
    }
    u64x2 u = __builtin_bit_cast(u64x2, r);
    unsigned long long* dst = reinterpret_cast<unsigned long long*>(out + i * 8);
    __hip_atomic_store(dst + 0, u[0], __ATOMIC_RELAXED, __HIP_MEMORY_SCOPE_AGENT);
    __hip_atomic_store(dst + 1, u[1], __ATOMIC_RELAXED, __HIP_MEMORY_SCOPE_AGENT);
  }
}

// ---------------- fallback (only if ws too small / odd shapes) ----------------
__global__ void naive_kernel(const float* __restrict__ x, const float* __restrict__ W,
                             const float* __restrict__ b, float* __restrict__ out,
                             int M, int N, int K) {
  int o = blockIdx.x * blockDim.x + threadIdx.x;
  int m = blockIdx.y;
  if (o >= N || m >= M) return;
  float s = 0.f;
  for (int k = 0; k < K; ++k) {
    float qx = rintf(x[(size_t)m * K + k] * 100.f) / 100.f;
    float qw = rintf(W[(size_t)o * K + k] * 100.f) / 100.f;
    s += qx * qw;
  }
  float v = s + b[o];
  __hip_atomic_store(out + (size_t)m * N + o, v, __ATOMIC_RELAXED,
                     __HIP_MEMORY_SCOPE_AGENT);
}

// ---------------- bf16 GEMM, B^T input: C[m][n] = sum_k A[m][k]*B[n][k] + bias[n]
// m97 structure: 128^2 tile, BK=32, 4 waves (2x2 of 64x64), global_load_lds w16,
// XOR slot swizzle (pre-swizzled global source + swizzled ds_read; rule #21).
__device__ __forceinline__ void gload_lds16(const bf16_t* g, const char* l) {
  __builtin_amdgcn_global_load_lds(
      (const __attribute__((address_space(1))) unsigned int*)g,
      (__attribute__((address_space(3))) unsigned int*)l, 16, 0, 0);
}

__global__ __launch_bounds__(THREADS) void gemm_bt_bf16(
    const bf16_t* __restrict__ A,   // [M][K]
    const bf16_t* __restrict__ B,   // [N][K]
    const float* __restrict__ bias, // [N]
    float* __restrict__ C,          // [M][N]
    int M, int N, int K) {
  __shared__ char sA[TILE * BK * 2];  // 8 KiB, row-major [128][32] bf16, slot-swizzled
  __shared__ char sB[TILE * BK * 2];

  const int tid = threadIdx.x;
  const int lane = tid & 63;
  const int wave = tid >> 6;  // 0..3
  const int wm = wave >> 1;   // 0..1 row-half of tile
  const int wn = wave & 1;    // 0..1 col-half of tile

  // XCD-aware block swizzle (bijective since nwg % 8 == 0 is checked)
  int nbn = N / TILE;
  int nwg = gridDim.x;
  int bid = blockIdx.x;
  int swz = bid;
  if ((nwg & 7) == 0) {
    int cpx = nwg >> 3;
    swz = (bid & 7) * cpx + (bid >> 3);
  }
  const int bm = swz / nbn;
  const int bn = swz % nbn;
  const int brow = bm * TILE;
  const int bcol = bn * TILE;

  // Staging: tile = 128 rows x 64 B. 2 issues x 256 threads x 16 B per tile.
  // LDS linear byte L -> (row = L>>6, stored slot = (L>>4)&3).
  // Stored slot sp holds global slot sp ^ ((row>>1)&3)  (involution).
  const int L0 = tid * 16;
  const int L1 = 4096 + tid * 16;
  const int row0 = L0 >> 6, row1 = L1 >> 6;
  const int slot0 = ((L0 >> 4) & 3) ^ ((row0 >> 1) & 3);
  const int slot1 = ((L1 >> 4) & 3) ^ ((row1 >> 1) & 3);
  const size_t aoff0 = (size_t)(brow + row0) * K + slot0 * 8;
  const size_t aoff1 = (size_t)(brow + row1) * K + slot1 * 8;
  const size_t boff0 = (size_t)(bcol + row0) * K + slot0 * 8;
  const size_t boff1 = (size_t)(bcol + row1) * K + slot1 * 8;

  // ds_read fragment byte offsets (loop-invariant)
  int abyte[4], bbyte[4];
#pragma unroll
  for (int f = 0; f < 4; ++f) {
    int ra = wm * 64 + f * 16 + (lane & 15);
    abyte[f] = ra * 64 + ((((lane >> 4) ^ (ra >> 1)) & 3) << 4);
    int rb = wn * 64 + f * 16 + (lane & 15);
    bbyte[f] = rb * 64 + ((((lane >> 4) ^ (rb >> 1)) & 3) << 4);
  }

  f32x4 acc[4][4];
#pragma unroll
  for (int m = 0; m < 4; ++m)
#pragma unroll
    for (int n = 0; n < 4; ++n) acc[m][n] = (f32x4){0.f, 0.f, 0.f, 0.f};

  for (int k0 = 0; k0 < K; k0 += BK) {
    __syncthreads();  // previous compute done reading LDS
    gload_lds16(A + aoff0 + k0, sA + L0);
    gload_lds16(A + aoff1 + k0, sA + L1);
    gload_lds16(B + boff0 + k0, sB + L0);
    gload_lds16(B + boff1 + k0, sB + L1);
    // Explicit drain of the LDS-DMA queue before the barrier (insurance in case
    // the compiler's pre-barrier waitcnt mis-models global_load_lds).
    asm volatile("s_waitcnt vmcnt(0)" ::: "memory");
    __builtin_amdgcn_sched_barrier(0);
    __syncthreads();  // staging visible to all waves

    bf16x8 af[4], bfr[4];
#pragma unroll
    for (int f = 0; f < 4; ++f) {
      af[f] = *reinterpret_cast<const bf16x8*>(sA + abyte[f]);
      bfr[f] = *reinterpret_cast<const bf16x8*>(sB + bbyte[f]);
    }
#pragma unroll
    for (int m = 0; m < 4; ++m)
#pragma unroll
      for (int n = 0; n < 4; ++n)
        acc[m][n] = __builtin_amdgcn_mfma_f32_16x16x32_bf16(af[m], bfr[n],
                                                            acc[m][n], 0, 0, 0);
  }

  // Epilogue: C/D layout col=lane&15, row=(lane>>4)*4+reg  [m89/m91]
  // Agent-scope stores: device-visible past per-XCD L2 regardless of graph fences.
  const int cn = lane & 15;
  const int r4 = (lane >> 4) << 2;
#pragma unroll
  for (int n = 0; n < 4; ++n) {
    const int gcol = bcol + wn * 64 + n * 16 + cn;
    const float bv = bias[gcol];
#pragma unroll
    for (int m = 0; m < 4; ++m) {
      const int grow = brow + wm * 64 + m * 16 + r4;
      float* outp = C + (size_t)grow * N + gcol;
#pragma unroll
      for (int j = 0; j < 4; ++j) {
        float v = acc[m][n][j] + bv;
        __hip_atomic_store(outp + (size_t)j * N, v, __ATOMIC_RELAXED,
                           __HIP_MEMORY_SCOPE_AGENT);
      }
    }
  }
}

extern "C" void kernel_launch(void* const* d_in, const int* in_sizes, int n_in,
                              void* d_out, int out_size, void* d_ws, size_t ws_size,
                              hipStream_t stream) {
  const float* x = (const float*)d_in[0];
  const float* W = (const float*)d_in[1];
  const float* b = (const float*)d_in[2];
  float* out = (float*)d_out;

  const int N = in_sizes[2];       // D_OUT
  const int K = in_sizes[1] / N;   // D_IN
  const int M = in_sizes[0] / K;   // B rows

  const size_t needA = (size_t)M * K * sizeof(bf16_t);
  const size_t needB = (size_t)N * K * sizeof(bf16_t);
  const bool tiled_ok = (M % TILE == 0) && (N % TILE == 0) && (K % BK == 0) &&
                        (ws_size >= needA + needB);
  if (!tiled_ok) {
    dim3 g((unsigned)((N + 255) / 256), (unsigned)M);
    naive_kernel<<<g, 256, 0, stream>>>(x, W, b, out, M, N, K);
    return;
  }

  bf16_t* qA = (bf16_t*)d_ws;
  bf16_t* qB = (bf16_t*)((char*)d_ws + needA);
  quant_bf16_kernel<<<2048, 256, 0, stream>>>(x, qA, (long)M * K / 8);
  quant_bf16_kernel<<<2048, 256, 0, stream>>>(W, qB, (long)N * K / 8);

  const int nwg = (M / TILE) * (N / TILE);
  gemm_bt_bf16<<<nwg, THREADS, 0, stream>>>(qA, qB, b, out, M, N, K);
}

// Round 3
// 174.700 us; speedup vs baseline: 1.3216x; 1.3216x over previous
//
#include <hip/hip_runtime.h>
#include <hip/hip_bf16.h>
#include <stdint.h>

typedef __hip_bfloat16 bf16_t;
typedef __attribute__((ext_vector_type(8))) __bf16 bf16x8;
typedef __attribute__((ext_vector_type(4))) float f32x4;
typedef __attribute__((ext_vector_type(8))) unsigned short ushort8;
typedef __attribute__((ext_vector_type(2))) unsigned long long u64x2;

#define BM 256
#define BN 256
#define BKT 32
#define THREADS 512
// per K-tile buffer: sA [256][32] bf16 = 16 KiB, sB same -> 32 KiB; x3 buffers = 96 KiB
#define ABYTES 16384
#define BUFBYTES 32768
#define LDS_TOTAL 98304

// ---------------- fused quantize: q = rint(v*100)/100, cast to bf16 ----------------
// One launch covers both x -> qA and W -> qB (qA,qB contiguous in d_ws).
// Agent-scope stores: visible to the GEMM kernel on any XCD under graph replay.
__global__ __launch_bounds__(256) void quant2_bf16_kernel(
    const float* __restrict__ x, const float* __restrict__ w,
    bf16_t* __restrict__ q, long axn8, long totn8) {
  long idx = (long)blockIdx.x * blockDim.x + threadIdx.x;
  long stride = (long)gridDim.x * blockDim.x;
  for (long i = idx; i < totn8; i += stride) {
    const float* src = (i < axn8) ? (x + i * 8) : (w + (i - axn8) * 8);
    const float4* p = reinterpret_cast<const float4*>(src);
    float4 v0 = p[0];
    float4 v1 = p[1];
    float vv[8] = {v0.x, v0.y, v0.z, v0.w, v1.x, v1.y, v1.z, v1.w};
    ushort8 r;
#pragma unroll
    for (int j = 0; j < 8; ++j) {
      float qq = rintf(vv[j] * 100.0f) / 100.0f;  // half-to-even, matches jnp.round
      __hip_bfloat16 h = __float2bfloat16(qq);
      r[j] = __builtin_bit_cast(unsigned short, h);
    }
    u64x2 u = __builtin_bit_cast(u64x2, r);
    unsigned long long* dst = reinterpret_cast<unsigned long long*>(q + i * 8);
    __hip_atomic_store(dst + 0, u[0], __ATOMIC_RELAXED, __HIP_MEMORY_SCOPE_AGENT);
    __hip_atomic_store(dst + 1, u[1], __ATOMIC_RELAXED, __HIP_MEMORY_SCOPE_AGENT);
  }
}

// ---------------- fallback (only if ws too small / odd shapes) ----------------
__global__ void naive_kernel(const float* __restrict__ x, const float* __restrict__ W,
                             const float* __restrict__ b, float* __restrict__ out,
                             int M, int N, int K) {
  int o = blockIdx.x * blockDim.x + threadIdx.x;
  int m = blockIdx.y;
  if (o >= N || m >= M) return;
  float s = 0.f;
  for (int k = 0; k < K; ++k) {
    float qx = rintf(x[(size_t)m * K + k] * 100.f) / 100.f;
    float qw = rintf(W[(size_t)o * K + k] * 100.f) / 100.f;
    s += qx * qw;
  }
  float v = s + b[o];
  __hip_atomic_store(out + (size_t)m * N + o, v, __ATOMIC_RELAXED,
                     __HIP_MEMORY_SCOPE_AGENT);
}

__device__ __forceinline__ void gload_lds16(const bf16_t* g, const char* l) {
  __builtin_amdgcn_global_load_lds(
      (const __attribute__((address_space(1))) unsigned int*)g,
      (__attribute__((address_space(3))) unsigned int*)l, 16, 0, 0);
}

// ---------------- bf16 GEMM, B^T input: C[m][n] = sum_k A[m][k]*B[n][k] + bias[n]
// 256^2 tile, BK=32, 8 waves (2x4; each wave 128x64 output = acc[8][4]).
// Triple-buffered LDS + counted vmcnt(4) + ONE raw s_barrier per K-step:
//   iter t: vmcnt(4)  -> tile t's 4 stage loads retired, tile t+1's 4 in flight
//           s_barrier -> all waves done reading buf[(t-1)%3] (reads precede their
//                        barrier in program order), tile t's LDS fully landed
//           STAGE(t+2) into buf[(t+2)%3] == buf[(t-1)%3]  (safe: see barrier above)
//           12 ds_read_b128 + 32 MFMA (compiler-scheduled, no pinning)
// XOR slot swizzle on 64B rows (stored slot = slot ^ ((row>>1)&3)): measured 0
// bank conflicts in round 2 with identical geometry. Pre-swizzled global source.
__global__ __launch_bounds__(THREADS, 2) void gemm_bt_bf16(
    const bf16_t* __restrict__ A,   // [M][K]
    const bf16_t* __restrict__ B,   // [N][K]
    const float* __restrict__ bias, // [N]
    float* __restrict__ C,          // [M][N]
    int M, int N, int K) {
  extern __shared__ char lds[];

  const int tid = threadIdx.x;
  const int lane = tid & 63;
  const int wave = tid >> 6;  // 0..7
  const int wm = wave >> 2;   // 0..1 -> output rows wm*128..+128
  const int wn = wave & 3;    // 0..3 -> output cols wn*64..+64

  // XCD-aware bijective swizzle (nwg=256 % 8 == 0 guaranteed by tiled_ok)
  int nbn = N / BN;
  int nwg = gridDim.x;
  int bid = blockIdx.x;
  int swz = bid;
  if ((nwg & 7) == 0) {
    int cpx = nwg >> 3;
    swz = (bid & 7) * cpx + (bid >> 3);
  }
  const int bm = swz / nbn;
  const int bn = swz % nbn;
  const int brow = bm * BM;
  const int bcol = bn * BN;

  // Staging: per tile, A = 256 rows x 64 B = 16 KiB = 512 thr x 16 B x 2 issues.
  // Linear LDS dest L -> row = L>>6, slot = (L>>4)&3. Stored slot holds global
  // slot (slot ^ ((row>>1)&3)) -> pre-swizzle the global source (involution).
  const int row0 = tid >> 2;        // 0..127
  const int row1 = 128 + row0;      // 128..255
  const int slot0 = (tid & 3) ^ ((row0 >> 1) & 3);
  const int slot1 = (tid & 3) ^ ((row1 >> 1) & 3);
  const int L0 = tid * 16;          // bytes 0..8191
  const int L1 = 8192 + tid * 16;   // bytes 8192..16383
  const size_t aoff0 = (size_t)(brow + row0) * K + slot0 * 8;
  const size_t aoff1 = (size_t)(brow + row1) * K + slot1 * 8;
  const size_t boff0 = (size_t)(bcol + row0) * K + slot0 * 8;
  const size_t boff1 = (size_t)(bcol + row1) * K + slot1 * 8;

  // ds_read fragment byte offsets (loop-invariant; swizzled to match store)
  int abyte[8], bbyte[4];
#pragma unroll
  for (int m = 0; m < 8; ++m) {
    int ra = wm * 128 + m * 16 + (lane & 15);
    abyte[m] = ra * 64 + ((((lane >> 4) ^ (ra >> 1)) & 3) << 4);
  }
#pragma unroll
  for (int n = 0; n < 4; ++n) {
    int rb = wn * 64 + n * 16 + (lane & 15);
    bbyte[n] = rb * 64 + ((((lane >> 4) ^ (rb >> 1)) & 3) << 4);
  }

  f32x4 acc[8][4];
#pragma unroll
  for (int m = 0; m < 8; ++m)
#pragma unroll
    for (int n = 0; n < 4; ++n) acc[m][n] = (f32x4){0.f, 0.f, 0.f, 0.f};

  const int nt = K / BKT;

  auto STAGE = [&](int kt, int q) {
    char* base = lds + q * BUFBYTES;
    const size_t kk = (size_t)kt * BKT;
    gload_lds16(A + aoff0 + kk, base + L0);
    gload_lds16(A + aoff1 + kk, base + L1);
    gload_lds16(B + boff0 + kk, base + ABYTES + L0);
    gload_lds16(B + boff1 + kk, base + ABYTES + L1);
  };

  auto COMPUTE = [&](int q) {
    const char* sA = lds + q * BUFBYTES;
    const char* sB = sA + ABYTES;
    bf16x8 af[8], bf[4];
#pragma unroll
    for (int m = 0; m < 8; ++m) af[m] = *reinterpret_cast<const bf16x8*>(sA + abyte[m]);
#pragma unroll
    for (int n = 0; n < 4; ++n) bf[n] = *reinterpret_cast<const bf16x8*>(sB + bbyte[n]);
#pragma unroll
    for (int m = 0; m < 8; ++m)
#pragma unroll
      for (int n = 0; n < 4; ++n)
        acc[m][n] = __builtin_amdgcn_mfma_f32_16x16x32_bf16(af[m], bf[n],
                                                            acc[m][n], 0, 0, 0);
  };

  // Prologue: 2 tiles in flight.
  STAGE(0, 0);
  STAGE(1, 1);

  int q = 0, q2 = 2;
  for (int t = 0; t < nt - 1; ++t) {
    asm volatile("s_waitcnt vmcnt(4)" ::: "memory");  // tile t landed; t+1 in flight
    __builtin_amdgcn_s_barrier();                     // raw: no vmcnt(0) drain
    asm volatile("" ::: "memory");
    if (t + 2 < nt) STAGE(t + 2, q2);
    COMPUTE(q);
    q = (q == 2) ? 0 : q + 1;
    q2 = (q2 == 2) ? 0 : q2 + 1;
  }
  // Final tile: drain everything.
  asm volatile("s_waitcnt vmcnt(0)" ::: "memory");
  __builtin_amdgcn_s_barrier();
  asm volatile("" ::: "memory");
  COMPUTE(q);

  // Epilogue: C/D layout col=lane&15, row=(lane>>4)*4+reg  [m89/m91]
  // Agent-scope stores (replay-safe visibility past per-XCD L2).
  const int cn = lane & 15;
  const int r4 = (lane >> 4) << 2;
#pragma unroll
  for (int n = 0; n < 4; ++n) {
    const int gcol = bcol + wn * 64 + n * 16 + cn;
    const float bv = bias[gcol];
#pragma unroll
    for (int m = 0; m < 8; ++m) {
      const int grow = brow + wm * 128 + m * 16 + r4;
      float* outp = C + (size_t)grow * N + gcol;
#pragma unroll
      for (int j = 0; j < 4; ++j) {
        float v = acc[m][n][j] + bv;
        __hip_atomic_store(outp + (size_t)j * N, v, __ATOMIC_RELAXED,
                           __HIP_MEMORY_SCOPE_AGENT);
      }
    }
  }
}

extern "C" void kernel_launch(void* const* d_in, const int* in_sizes, int n_in,
                              void* d_out, int out_size, void* d_ws, size_t ws_size,
                              hipStream_t stream) {
  const float* x = (const float*)d_in[0];
  const float* W = (const float*)d_in[1];
  const float* b = (const float*)d_in[2];
  float* out = (float*)d_out;

  const int N = in_sizes[2];       // D_OUT
  const int K = in_sizes[1] / N;   // D_IN
  const int M = in_sizes[0] / K;   // B rows

  const size_t needA = (size_t)M * K * sizeof(bf16_t);
  const size_t needB = (size_t)N * K * sizeof(bf16_t);
  const bool tiled_ok = (M % BM == 0) && (N % BN == 0) && (K % BKT == 0) &&
                        (K / BKT >= 2) && (ws_size >= needA + needB);
  if (!tiled_ok) {
    dim3 g((unsigned)((N + 255) / 256), (unsigned)M);
    naive_kernel<<<g, 256, 0, stream>>>(x, W, b, out, M, N, K);
    return;
  }

  bf16_t* qA = (bf16_t*)d_ws;
  bf16_t* qB = qA + (size_t)M * K;
  const long axn8 = (long)M * K / 8;
  const long totn8 = axn8 + (long)N * K / 8;
  quant2_bf16_kernel<<<2048, 256, 0, stream>>>(x, W, qA, axn8, totn8);

  // >64 KiB dynamic LDS opt-in (host-side, graph-capture-safe, deterministic).
  (void)hipFuncSetAttribute((const void*)gemm_bt_bf16,
                            hipFuncAttributeMaxDynamicSharedMemorySize, LDS_TOTAL);

  const int nwg = (M / BM) * (N / BN);
  gemm_bt_bf16<<<nwg, THREADS, LDS_TOTAL, stream>>>(qA, qB, b, out, M, N, K);
}

// Round 4
// 163.711 us; speedup vs baseline: 1.4103x; 1.0671x over previous
//
#include <hip/hip_runtime.h>
#include <hip/hip_bf16.h>
#include <stdint.h>

typedef __hip_bfloat16 bf16_t;
typedef __attribute__((ext_vector_type(8))) __bf16 bf16x8;
typedef __attribute__((ext_vector_type(4))) float f32x4;
typedef __attribute__((ext_vector_type(8))) unsigned short ushort8;
typedef __attribute__((ext_vector_type(2))) unsigned long long u64x2;

#define BM 256
#define BN 256
#define BK 64
#define THREADS 512
#define OPBYTES 32768   // one operand per buf: 256 rows x 128 B
#define BUFBYTES 65536  // A + B
#define LDS_TOTAL 131072

// ---------------- fused quantize: q = rint(v*100)/100, cast to bf16 ----------------
__global__ __launch_bounds__(256) void quant2_bf16_kernel(
    const float* __restrict__ x, const float* __restrict__ w,
    bf16_t* __restrict__ q, long axn8, long totn8) {
  long idx = (long)blockIdx.x * blockDim.x + threadIdx.x;
  long stride = (long)gridDim.x * blockDim.x;
  for (long i = idx; i < totn8; i += stride) {
    const float* src = (i < axn8) ? (x + i * 8) : (w + (i - axn8) * 8);
    const float4* p = reinterpret_cast<const float4*>(src);
    float4 v0 = p[0];
    float4 v1 = p[1];
    float vv[8] = {v0.x, v0.y, v0.z, v0.w, v1.x, v1.y, v1.z, v1.w};
    ushort8 r;
#pragma unroll
    for (int j = 0; j < 8; ++j) {
      float qq = rintf(vv[j] * 100.0f) / 100.0f;  // half-to-even, matches jnp.round
      __hip_bfloat16 h = __float2bfloat16(qq);
      r[j] = __builtin_bit_cast(unsigned short, h);
    }
    u64x2 u = __builtin_bit_cast(u64x2, r);
    unsigned long long* dst = reinterpret_cast<unsigned long long*>(q + i * 8);
    __hip_atomic_store(dst + 0, u[0], __ATOMIC_RELAXED, __HIP_MEMORY_SCOPE_AGENT);
    __hip_atomic_store(dst + 1, u[1], __ATOMIC_RELAXED, __HIP_MEMORY_SCOPE_AGENT);
  }
}

// ---------------- fallback ----------------
__global__ void naive_kernel(const float* __restrict__ x, const float* __restrict__ W,
                             const float* __restrict__ b, float* __restrict__ out,
                             int M, int N, int K) {
  int o = blockIdx.x * blockDim.x + threadIdx.x;
  int m = blockIdx.y;
  if (o >= N || m >= M) return;
  float s = 0.f;
  for (int k = 0; k < K; ++k) {
    float qx = rintf(x[(size_t)m * K + k] * 100.f) / 100.f;
    float qw = rintf(W[(size_t)o * K + k] * 100.f) / 100.f;
    s += qx * qw;
  }
  float v = s + b[o];
  __hip_atomic_store(out + (size_t)m * N + o, v, __ATOMIC_RELAXED,
                     __HIP_MEMORY_SCOPE_AGENT);
}

__device__ __forceinline__ void gload_lds16(const bf16_t* g, const char* l) {
  __builtin_amdgcn_global_load_lds(
      (const __attribute__((address_space(1))) unsigned int*)g,
      (__attribute__((address_space(3))) unsigned int*)l, 16, 0, 0);
}

#define BARRIER()                               \
  do {                                          \
    asm volatile("" ::: "memory");              \
    __builtin_amdgcn_s_barrier();               \
    asm volatile("" ::: "memory");              \
  } while (0)
#define LGKM0() asm volatile("s_waitcnt lgkmcnt(0)" ::: "memory")
#define VM4() asm volatile("s_waitcnt vmcnt(4)" ::: "memory")

// ---------------- bf16 GEMM, B^T input: C[m][n] = sum_k A[m][k]*B[n][k] + bias[n]
// 8-phase template (T3+T4+T5): BM=BN=256, BK=64, 8 waves (2x4; each 128x64 out).
// 2 LDS K-tile buffers; per phase: {ds_read quadrant frags | stage 1 half-tile
// (2 global_load_lds) -> barrier -> lgkmcnt(0) -> setprio(1) -> 16 MFMA ->
// setprio(0) -> barrier}; counted vmcnt(4) only at phases 4 and 8.
// Stage slots: ph1 b1.A0(t1) ph2 b1.A1(t1) ph3 b0.B0(t0+2) ph4 b0.B1 ph5 b0.A0
// ph6 b0.A1 ph7 b1.B0(t1+2) ph8 b1.B1. Every overwrite separated from the last
// read of that half by >=1 full barrier pair (derivation in session journal).
// LDS swizzle: 128B rows, stored slot = slot ^ (row&7) (involution; 2 lanes/bank
// on ds_read_b128 = free per m136). global_load_lds dest is linear in lane
// (base+lane*16); swizzle applied on the global SOURCE address (rule #21).
__global__ __launch_bounds__(THREADS, 2) void gemm_bt_bf16(
    const bf16_t* __restrict__ A,   // [M][K]
    const bf16_t* __restrict__ B,   // [N][K]
    const float* __restrict__ bias, // [N]
    float* __restrict__ C,          // [M][N]
    int M, int N, int K) {
  extern __shared__ char lds[];

  const int tid = threadIdx.x;
  const int lane = tid & 63;
  const int wave = tid >> 6;  // 0..7
  const int wm = wave >> 2;   // 0..1 -> output rows wm*128..+128
  const int wn = wave & 3;    // 0..3 -> output cols wn*64..+64
  const int lr = lane & 15;
  const int lg = lane >> 4;

  // XCD-aware bijective swizzle (nwg % 8 == 0 guaranteed by tiled_ok)
  int nbn = N / BN;
  int nwg = gridDim.x;
  int bid = blockIdx.x;
  int swz = bid;
  if ((nwg & 7) == 0) {
    int cpx = nwg >> 3;
    swz = (bid & 7) * cpx + (bid >> 3);
  }
  const int brow = (swz / nbn) * BM;
  const int bcol = (swz % nbn) * BN;

  // ds_read byte offsets within an operand region (kk=0; kk=1 is ^64: slot bit2)
  int aoffs[8], boffs[4];
#pragma unroll
  for (int m = 0; m < 8; ++m) {
    int r = wm * 128 + m * 16 + lr;
    aoffs[m] = r * 128 + (((lg) ^ (r & 7)) << 4);
  }
#pragma unroll
  for (int n = 0; n < 4; ++n) {
    int r = wn * 64 + n * 16 + lr;
    boffs[n] = r * 128 + (((lg) ^ (r & 7)) << 4);
  }

  f32x4 acc[8][4];
#pragma unroll
  for (int m = 0; m < 8; ++m)
#pragma unroll
    for (int n = 0; n < 4; ++n) acc[m][n] = (f32x4){0.f, 0.f, 0.f, 0.f};

  const int nt = K / BK;

  // Stage one half-tile (16 KiB = 2 x 512thr x 16B). Linear LDS dest
  // (= base + lane*16 within each wave); inverse swizzle on global source.
  auto STAGE_A = [&](int h, int kt, int q) {
#pragma unroll
    for (int i = 0; i < 2; ++i) {
      int row = h * 128 + i * 64 + (tid >> 3);
      int L = q * BUFBYTES + row * 128 + ((tid & 7) << 4);
      int slot = (tid & 7) ^ (row & 7);
      gload_lds16(A + (size_t)(brow + row) * K + (size_t)kt * 64 + slot * 8,
                  lds + L);
    }
  };
  auto STAGE_B = [&](int h, int kt, int q) {
#pragma unroll
    for (int i = 0; i < 2; ++i) {
      int row = h * 128 + i * 64 + (tid >> 3);
      int L = q * BUFBYTES + OPBYTES + row * 128 + ((tid & 7) << 4);
      int slot = (tid & 7) ^ (row & 7);
      gload_lds16(B + (size_t)(bcol + row) * K + (size_t)kt * 64 + slot * 8,
                  lds + L);
    }
  };

  bf16x8 aq[8], blo[4], bhi[4];  // A quadrant [mm][kk]; B quadrants [nn][kk]
  auto READ_A = [&](int q, int mh) {
#pragma unroll
    for (int mm = 0; mm < 4; ++mm) {
      int off = q * BUFBYTES + aoffs[mh * 4 + mm];
      aq[mm * 2 + 0] = *reinterpret_cast<const bf16x8*>(lds + off);
      aq[mm * 2 + 1] = *reinterpret_cast<const bf16x8*>(lds + (off ^ 64));
    }
  };
  auto READ_B = [&](int q, int nh, bf16x8* dst) {
#pragma unroll
    for (int nn = 0; nn < 2; ++nn) {
      int off = q * BUFBYTES + OPBYTES + boffs[nh * 2 + nn];
      dst[nn * 2 + 0] = *reinterpret_cast<const bf16x8*>(lds + off);
      dst[nn * 2 + 1] = *reinterpret_cast<const bf16x8*>(lds + (off ^ 64));
    }
  };
  auto MMA = [&](int mh, int nh, const bf16x8* bb) {
    __builtin_amdgcn_s_setprio(1);
#pragma unroll
    for (int mm = 0; mm < 4; ++mm)
#pragma unroll
      for (int nn = 0; nn < 2; ++nn)
#pragma unroll
        for (int kk = 0; kk < 2; ++kk)
          acc[mh * 4 + mm][nh * 2 + nn] = __builtin_amdgcn_mfma_f32_16x16x32_bf16(
              aq[mm * 2 + kk], bb[nn * 2 + kk], acc[mh * 4 + mm][nh * 2 + nn],
              0, 0, 0);
    __builtin_amdgcn_s_setprio(0);
  };

  // Prologue: buf0 <- tile0 (B0,B1,A0,A1), buf1 <- tile1 B halves. Ages match
  // the steady-state assumption of the ph4/ph8 vmcnt(4) counts.
  STAGE_B(0, 0, 0);
  STAGE_B(1, 0, 0);
  STAGE_A(0, 0, 0);
  STAGE_A(1, 0, 0);
  STAGE_B(0, 1, 1);
  STAGE_B(1, 1, 1);
  VM4();  // retire buf0's 4 halves (retain newest 4 loads = b1.B0/B1)
  BARRIER();

  const int np = nt >> 1;
  for (int p = 0; p < np; ++p) {
    const int t0 = 2 * p, t1 = t0 + 1;
    const bool more = (t0 + 2 < nt);  // uniform across block
    // ph1: buf0 quad (m-lo, n-lo)
    READ_A(0, 0);
    READ_B(0, 0, blo);
    STAGE_A(0, t1, 1);
    BARRIER(); LGKM0();
    MMA(0, 0, blo);
    BARRIER();
    // ph2: (m-lo, n-hi)
    READ_B(0, 1, bhi);
    STAGE_A(1, t1, 1);
    BARRIER(); LGKM0();
    MMA(0, 1, bhi);
    BARRIER();
    // ph3: (m-hi, n-hi)
    READ_A(0, 1);
    if (more) STAGE_B(0, t0 + 2, 0);
    BARRIER(); LGKM0();
    MMA(1, 1, bhi);
    BARRIER();
    // ph4: (m-hi, n-lo) — no reads; counted vmcnt for buf1's halves
    if (more) STAGE_B(1, t0 + 2, 0);
    BARRIER();
    MMA(1, 0, blo);
    VM4();
    BARRIER();
    // ph5: buf1 quad (m-lo, n-lo)
    READ_A(1, 0);
    READ_B(1, 0, blo);
    if (more) STAGE_A(0, t0 + 2, 0);
    BARRIER(); LGKM0();
    MMA(0, 0, blo);
    BARRIER();
    // ph6
    READ_B(1, 1, bhi);
    if (more) STAGE_A(1, t0 + 2, 0);
    BARRIER(); LGKM0();
    MMA(0, 1, bhi);
    BARRIER();
    // ph7
    READ_A(1, 1);
    if (more) STAGE_B(0, t1 + 2, 1);
    BARRIER(); LGKM0();
    MMA(1, 1, bhi);
    BARRIER();
    // ph8 — counted vmcnt for next period's buf0 halves
    if (more) STAGE_B(1, t1 + 2, 1);
    BARRIER();
    MMA(1, 0, blo);
    VM4();
    BARRIER();
  }

  // Epilogue: C/D layout col=lane&15, row=(lane>>4)*4+reg  [m89/m91]
  // Agent-scope stores (replay-safe visibility past per-XCD L2).
  const int cn = lane & 15;
  const int r4 = (lane >> 4) << 2;
#pragma unroll
  for (int n = 0; n < 4; ++n) {
    const int gcol = bcol + wn * 64 + n * 16 + cn;
    const float bv = bias[gcol];
#pragma unroll
    for (int m = 0; m < 8; ++m) {
      const int grow = brow + wm * 128 + m * 16 + r4;
      float* outp = C + (size_t)grow * N + gcol;
#pragma unroll
      for (int j = 0; j < 4; ++j) {
        float v = acc[m][n][j] + bv;
        __hip_atomic_store(outp + (size_t)j * N, v, __ATOMIC_RELAXED,
                           __HIP_MEMORY_SCOPE_AGENT);
      }
    }
  }
}

extern "C" void kernel_launch(void* const* d_in, const int* in_sizes, int n_in,
                              void* d_out, int out_size, void* d_ws, size_t ws_size,
                              hipStream_t stream) {
  const float* x = (const float*)d_in[0];
  const float* W = (const float*)d_in[1];
  const float* b = (const float*)d_in[2];
  float* out = (float*)d_out;

  const int N = in_sizes[2];       // D_OUT
  const int K = in_sizes[1] / N;   // D_IN
  const int M = in_sizes[0] / K;   // B rows

  const size_t needA = (size_t)M * K * sizeof(bf16_t);
  const size_t needB = (size_t)N * K * sizeof(bf16_t);
  const bool tiled_ok = (M % BM == 0) && (N % BN == 0) && (K % (2 * BK) == 0) &&
                        (K / BK >= 2) && (ws_size >= needA + needB);
  if (!tiled_ok) {
    dim3 g((unsigned)((N + 255) / 256), (unsigned)M);
    naive_kernel<<<g, 256, 0, stream>>>(x, W, b, out, M, N, K);
    return;
  }

  bf16_t* qA = (bf16_t*)d_ws;
  bf16_t* qB = qA + (size_t)M * K;
  const long axn8 = (long)M * K / 8;
  const long totn8 = axn8 + (long)N * K / 8;
  quant2_bf16_kernel<<<2048, 256, 0, stream>>>(x, W, qA, axn8, totn8);

  (void)hipFuncSetAttribute((const void*)gemm_bt_bf16,
                            hipFuncAttributeMaxDynamicSharedMemorySize, LDS_TOTAL);

  const int nwg = (M / BM) * (N / BN);
  gemm_bt_bf16<<<nwg, THREADS, LDS_TOTAL, stream>>>(qA, qB, b, out, M, N, K);
}